// Round 3
// baseline (15.343 us; speedup 1.0000x reference)
//
#include <hip/hip_runtime.h>

// FlashRecoModel: out[b,p,t] = sum_f pe[b,f,p]*conf[b,f] * w[b,f,t]
// w = Gaussian(center=clip(time*T,0,T-1), sigma) normalized over ticks.
// Tail beyond |z|=8 is exp(-32)~1.3e-14 -> truncated (threshold 1.8e-2).
//
// Tile-gather, latency-optimized: block = (b, 16-tick tile), 1024 blocks.
// Ballot-compacted flash list; pe loads prefetched (static 8-wide unroll)
// so HBM latency hides under the exp phase; direct per-thread 64B row
// writes (full-line, no transpose staging). LDS ~10 KB, 3 barriers.

#define F       128
#define TT      16     // ticks per tile
#define BLOCK   256    // == P
#define MAXSLOT 128    // worst case: all flashes hit one tile
#define CHUNK   8      // prefetch depth (covers typical count ~2-4)

__global__ __launch_bounds__(BLOCK) void flash_reco_tile(
    const float* __restrict__ pe,      // [B, F, P]
    const float* __restrict__ ftime,   // [B, F]
    const float* __restrict__ fconf,   // [B, F]
    const float* __restrict__ sig_p,   // scalar
    float* __restrict__ out,           // [B, P, T]
    int P, int T, int ntiles)
{
    __shared__ int   wcnt[4];
    __shared__ int   fl_f [MAXSLOT];
    __shared__ float fl_tb[MAXSLOT];
    __shared__ float fl_sc[MAXSLOT];   // conf, later conf/denom
    __shared__ int   fl_lo[MAXSLOT];
    __shared__ int   fl_len[MAXSLOT];
    __shared__ float wt[MAXSLOT * TT]; // 8 KB tile weights (unnormalized)

    const int tid  = threadIdx.x;
    const int b    = blockIdx.x / ntiles;
    const int tile = blockIdx.x % ntiles;
    const int t0   = tile * TT;
    const float sigma   = *sig_p;
    const float inv_sig = 1.0f / sigma;

    // ---- phase 1: flashes whose +-8sigma window intersects [t0, t0+TT) ----
    bool act = false;
    float tb = 0.f, cf = 0.f;
    int lo = 0, len = 0;
    if (tid < F) {
        const float tm = ftime[b * F + tid];
        cf = fconf[b * F + tid];
        tb = fminf(fmaxf(tm * (float)T, 0.0f), (float)(T - 1));
        const float r = 8.0f * sigma;
        lo = (int)ceilf(tb - r);       if (lo < 0) lo = 0;
        int hi = (int)floorf(tb + r);  if (hi > T - 1) hi = T - 1;
        len = hi - lo + 1;
        act = (lo <= t0 + TT - 1) && (hi >= t0);
    }
    const unsigned long long m = __ballot(act);
    const int lane = tid & 63, wv = tid >> 6;
    if (lane == 0) wcnt[wv] = __popcll(m);
    __syncthreads();
    const int count = wcnt[0] + wcnt[1];   // waves 2,3 ballot to 0
    if (act) {
        const int slot = __popcll(m & ((1ULL << lane) - 1ULL))
                       + (wv == 1 ? wcnt[0] : 0);
        fl_f[slot]  = tid;
        fl_tb[slot] = tb;
        fl_sc[slot] = cf;
        fl_lo[slot] = lo;
        fl_len[slot] = len;
    }
    __syncthreads();

    // ---- phase 2-pre: issue pe prefetch NOW (latency hides under exps) ----
    // Static unroll + predication: sv[] stays in registers (no scratch).
    float sv[CHUNK];
    #pragma unroll
    for (int u = 0; u < CHUNK; ++u)
        sv[u] = (u < count) ? pe[((long)b * F + fl_f[u]) * P + tid] : 0.0f;

    // ---- phase 2a: unnormalized tile weights, parallel over (slot, j) ----
    for (int idx = tid; idx < count * TT; idx += BLOCK) {
        const int a = idx >> 4, j = idx & (TT - 1);
        const float z = ((float)(t0 + j) - fl_tb[a]) * inv_sig;
        wt[idx] = __expf(-0.5f * z * z);
    }
    // ---- phase 2b: fold 1/denominator into the per-slot scale ----
    for (int a = tid; a < count; a += BLOCK) {
        const float tbv = fl_tb[a];
        const int lov = fl_lo[a], lenv = fl_len[a];
        float s = 0.0f;
        for (int k = 0; k < lenv; ++k) {
            const float z = ((float)(lov + k) - tbv) * inv_sig;
            s += __expf(-0.5f * z * z);
        }
        fl_sc[a] = fl_sc[a] / (s + 1e-10f);
    }
    __syncthreads();

    // ---- phase 3: per-thread (p = tid) register accumulation ----
    float acc[TT];
    #pragma unroll
    for (int j = 0; j < TT; ++j) acc[j] = 0.0f;

    #pragma unroll
    for (int a = 0; a < CHUNK; ++a) {
        if (a < count) {
            const float s = sv[a] * fl_sc[a];
            const float4* w4 = (const float4*)&wt[a * TT];  // uniform -> broadcast
            #pragma unroll
            for (int q = 0; q < TT / 4; ++q) {
                const float4 w = w4[q];
                acc[q*4+0] += s * w.x;
                acc[q*4+1] += s * w.y;
                acc[q*4+2] += s * w.z;
                acc[q*4+3] += s * w.w;
            }
        }
    }
    // rare tail (count > CHUNK)
    for (int a = CHUNK; a < count; ++a) {
        const float s = pe[((long)b * F + fl_f[a]) * P + tid] * fl_sc[a];
        const float4* w4 = (const float4*)&wt[a * TT];
        #pragma unroll
        for (int q = 0; q < TT / 4; ++q) {
            const float4 w = w4[q];
            acc[q*4+0] += s * w.x;
            acc[q*4+1] += s * w.y;
            acc[q*4+2] += s * w.z;
            acc[q*4+3] += s * w.w;
        }
    }

    // ---- phase 4: direct row write, 64B contiguous per thread (full lines) --
    float4* o4 = (float4*)(out + (long)b * P * T + (long)tid * T + t0);
    #pragma unroll
    for (int q = 0; q < TT / 4; ++q)
        o4[q] = make_float4(acc[q*4+0], acc[q*4+1], acc[q*4+2], acc[q*4+3]);
}

extern "C" void kernel_launch(void* const* d_in, const int* in_sizes, int n_in,
                              void* d_out, int out_size, void* d_ws, size_t ws_size,
                              hipStream_t stream) {
    const float* pe    = (const float*)d_in[0];  // [B,F,P]
    const float* ftime = (const float*)d_in[1];  // [B,F,1]
    const float* fconf = (const float*)d_in[2];  // [B,F,1]
    const float* sigma = (const float*)d_in[4];  // scalar

    const int BF = in_sizes[1];            // B*F = 1024
    const int P  = in_sizes[0] / BF;       // 256
    const int B  = BF / F;                 // 8
    const int T  = out_size / (B * P);     // 2048
    const int ntiles = (T + TT - 1) / TT;  // 128

    flash_reco_tile<<<dim3(B * ntiles), dim3(BLOCK), 0, stream>>>(
        pe, ftime, fconf, sigma, (float*)d_out, P, T, ntiles);
}

// Round 4
// 14.870 us; speedup vs baseline: 1.0318x; 1.0318x over previous
//
#include <hip/hip_runtime.h>

// FlashRecoModel: out[b,p,t] = sum_f pe[b,f,p]*conf[b,f] * w[b,f,t]
// w = Gaussian(center=clip(time*T,0,T-1), sigma) normalized over ticks.
// Tail beyond |z|=8 is exp(-32)~1.3e-14 -> truncated (threshold 1.8e-2).
//
// R4 = R2 structure (TT=32, 512 blocks) minus its two inefficiencies:
//  - direct per-thread row writes: 32 floats = 128B contiguous = full L2
//    lines (replaces 33KB LDS transpose + barrier)
//  - pe prefetch (8-deep, predicated, static) before the exp phase so HBM
//    latency hides under weight computation
// LDS ~17.5 KB, 2 barriers.

#define F       128
#define TT      32     // ticks per tile (32 floats = 128B rows -> full lines)
#define BLOCK   256    // == P
#define MAXSLOT 128    // worst case: all flashes hit one tile
#define CHUNK   8      // prefetch depth (typical count ~3)

__global__ __launch_bounds__(BLOCK) void flash_reco_tile(
    const float* __restrict__ pe,      // [B, F, P]
    const float* __restrict__ ftime,   // [B, F]
    const float* __restrict__ fconf,   // [B, F]
    const float* __restrict__ sig_p,   // scalar
    float* __restrict__ out,           // [B, P, T]
    int P, int T, int ntiles)
{
    __shared__ int   wcnt[4];
    __shared__ int   fl_f [MAXSLOT];
    __shared__ float fl_tb[MAXSLOT];
    __shared__ float fl_sc[MAXSLOT];   // conf, later conf/denom
    __shared__ int   fl_lo[MAXSLOT];
    __shared__ int   fl_len[MAXSLOT];
    __shared__ float wt[MAXSLOT * TT]; // 16 KB tile weights (unnormalized)

    const int tid  = threadIdx.x;
    const int b    = blockIdx.x / ntiles;
    const int tile = blockIdx.x % ntiles;
    const int t0   = tile * TT;
    const float sigma   = *sig_p;
    const float inv_sig = 1.0f / sigma;

    // ---- phase 1: flashes whose +-8sigma window intersects [t0, t0+TT) ----
    bool act = false;
    float tb = 0.f, cf = 0.f;
    int lo = 0, len = 0;
    if (tid < F) {
        const float tm = ftime[b * F + tid];
        cf = fconf[b * F + tid];
        tb = fminf(fmaxf(tm * (float)T, 0.0f), (float)(T - 1));
        const float r = 8.0f * sigma;
        lo = (int)ceilf(tb - r);       if (lo < 0) lo = 0;
        int hi = (int)floorf(tb + r);  if (hi > T - 1) hi = T - 1;
        len = hi - lo + 1;
        act = (lo <= t0 + TT - 1) && (hi >= t0);
    }
    const unsigned long long m = __ballot(act);
    const int lane = tid & 63, wv = tid >> 6;
    if (lane == 0) wcnt[wv] = __popcll(m);
    __syncthreads();
    const int count = wcnt[0] + wcnt[1];   // waves 2,3 ballot to 0
    if (act) {
        const int slot = __popcll(m & ((1ULL << lane) - 1ULL))
                       + (wv == 1 ? wcnt[0] : 0);
        fl_f[slot]  = tid;
        fl_tb[slot] = tb;
        fl_sc[slot] = cf;
        fl_lo[slot] = lo;
        fl_len[slot] = len;
    }
    __syncthreads();

    // ---- phase 2-pre: issue pe prefetch NOW (latency hides under exps) ----
    float sv[CHUNK];
    #pragma unroll
    for (int u = 0; u < CHUNK; ++u)
        sv[u] = (u < count) ? pe[((long)b * F + fl_f[u]) * P + tid] : 0.0f;

    // ---- phase 2a: unnormalized tile weights, parallel over (slot, j) ----
    for (int idx = tid; idx < count * TT; idx += BLOCK) {
        const int a = idx >> 5, j = idx & (TT - 1);
        const float z = ((float)(t0 + j) - fl_tb[a]) * inv_sig;
        wt[idx] = __expf(-0.5f * z * z);
    }
    // ---- phase 2b: fold 1/denominator into the per-slot scale ----
    for (int a = tid; a < count; a += BLOCK) {
        const float tbv = fl_tb[a];
        const int lov = fl_lo[a], lenv = fl_len[a];
        float s = 0.0f;
        for (int k = 0; k < lenv; ++k) {
            const float z = ((float)(lov + k) - tbv) * inv_sig;
            s += __expf(-0.5f * z * z);
        }
        fl_sc[a] = fl_sc[a] / (s + 1e-10f);
    }
    __syncthreads();

    // ---- phase 3: per-thread (p = tid) register accumulation ----
    float acc[TT];
    #pragma unroll
    for (int j = 0; j < TT; ++j) acc[j] = 0.0f;

    #pragma unroll
    for (int a = 0; a < CHUNK; ++a) {
        if (a < count) {
            const float s = sv[a] * fl_sc[a];
            const float4* w4 = (const float4*)&wt[a * TT];  // uniform -> broadcast
            #pragma unroll
            for (int q = 0; q < TT / 4; ++q) {
                const float4 w = w4[q];
                acc[q*4+0] += s * w.x;
                acc[q*4+1] += s * w.y;
                acc[q*4+2] += s * w.z;
                acc[q*4+3] += s * w.w;
            }
        }
    }
    // rare tail (count > CHUNK)
    for (int a = CHUNK; a < count; ++a) {
        const float s = pe[((long)b * F + fl_f[a]) * P + tid] * fl_sc[a];
        const float4* w4 = (const float4*)&wt[a * TT];
        #pragma unroll
        for (int q = 0; q < TT / 4; ++q) {
            const float4 w = w4[q];
            acc[q*4+0] += s * w.x;
            acc[q*4+1] += s * w.y;
            acc[q*4+2] += s * w.z;
            acc[q*4+3] += s * w.w;
        }
    }

    // ---- phase 4: direct row write, 128B contiguous per thread (full lines) -
    float4* o4 = (float4*)(out + (long)b * P * T + (long)tid * T + t0);
    #pragma unroll
    for (int q = 0; q < TT / 4; ++q)
        o4[q] = make_float4(acc[q*4+0], acc[q*4+1], acc[q*4+2], acc[q*4+3]);
}

extern "C" void kernel_launch(void* const* d_in, const int* in_sizes, int n_in,
                              void* d_out, int out_size, void* d_ws, size_t ws_size,
                              hipStream_t stream) {
    const float* pe    = (const float*)d_in[0];  // [B,F,P]
    const float* ftime = (const float*)d_in[1];  // [B,F,1]
    const float* fconf = (const float*)d_in[2];  // [B,F,1]
    const float* sigma = (const float*)d_in[4];  // scalar

    const int BF = in_sizes[1];            // B*F = 1024
    const int P  = in_sizes[0] / BF;       // 256
    const int B  = BF / F;                 // 8
    const int T  = out_size / (B * P);     // 2048
    const int ntiles = (T + TT - 1) / TT;  // 64

    flash_reco_tile<<<dim3(B * ntiles), dim3(BLOCK), 0, stream>>>(
        pe, ftime, fconf, sigma, (float*)d_out, P, T, ntiles);
}